// Round 4
// baseline (338.729 us; speedup 1.0000x reference)
//
#include <hip/hip_runtime.h>

// CoarseMatching on MI355X.
// Sizes: N=2, C=256, G0=G1=1600 (40x40), L0=L1=6400 (80x80), TOPK=8, K4=32.
// Outputs (flat f32, concat): h01 (2,6400,32) | h10 (2,32,6400) | scores (2,6400)
//   | j_best (2,6400, int-as-float) | mask (2,6400, 0/1) | x0_8x (2,256,80,80) | x1_8x.
// Workspace: sim + simT (40.96MB) + topk idx + h01p/h10p + score/jbest/ibest ~= 44.6MB.

#define N_B   2
#define C_DIM 256
#define G0N   1600
#define GW    40
#define L0N   6400
#define W_F   80
#define TK    8

// ---------------- K1: sim GEMM (A^T B, K=256) + transpose ----------------
// v2: 64x64 tile / 128 threads / 8x4 per thread / KC=32. Grid (25,25,2)=1250 blocks.
#define KC 32
__global__ __launch_bounds__(128) void k_sim(const float* __restrict__ p0,
                                             const float* __restrict__ p1,
                                             float* __restrict__ sim,
                                             float* __restrict__ simT) {
  const int n  = blockIdx.z;
  const int i0 = blockIdx.y * 64;
  const int j0 = blockIdx.x * 64;
  const float* A = p0 + (size_t)n * C_DIM * G0N;  // [c][i]
  const float* B = p1 + (size_t)n * C_DIM * G0N;  // [c][j]
  __shared__ float As[KC][64];
  __shared__ float Bs[KC][64];
  const int t  = threadIdx.x;
  const int tx = t & 15;   // 16 cols of 4  -> 64
  const int ty = t >> 4;   // 8 rows of 8   -> 64

  float4 acc[8];
#pragma unroll
  for (int ii = 0; ii < 8; ++ii) acc[ii] = make_float4(0.f, 0.f, 0.f, 0.f);

  for (int kc = 0; kc < C_DIM; kc += KC) {
    // stage 32x64 A-tile and B-tile: 512 float4 each, 4 per thread per tile
#pragma unroll
    for (int u = 0; u < 4; ++u) {
      int f   = t + u * 128;        // 0..511
      int row = f >> 4;             // 16 float4 per row
      int c4  = (f & 15) * 4;
      *(float4*)&As[row][c4] = *(const float4*)(A + (size_t)(kc + row) * G0N + i0 + c4);
      *(float4*)&Bs[row][c4] = *(const float4*)(B + (size_t)(kc + row) * G0N + j0 + c4);
    }
    __syncthreads();
#pragma unroll
    for (int k = 0; k < KC; ++k) {
      __attribute__((aligned(16))) float a[8];
      *(float4*)&a[0] = *(const float4*)&As[k][ty * 8];
      *(float4*)&a[4] = *(const float4*)&As[k][ty * 8 + 4];
      float4 bv = *(const float4*)&Bs[k][tx * 4];
#pragma unroll
      for (int ii = 0; ii < 8; ++ii) {
        acc[ii].x += a[ii] * bv.x;
        acc[ii].y += a[ii] * bv.y;
        acc[ii].z += a[ii] * bv.z;
        acc[ii].w += a[ii] * bv.w;
      }
    }
    __syncthreads();
  }

  float* simn  = sim  + (size_t)n * G0N * G0N;
  float* simTn = simT + (size_t)n * G0N * G0N;
  const int ib = i0 + ty * 8;
  const int jb = j0 + tx * 4;
  const float* accf = (const float*)acc;  // [ii*4 + jj]
#pragma unroll
  for (int ii = 0; ii < 8; ++ii)
    *(float4*)(simn + (size_t)(ib + ii) * G0N + jb) = acc[ii];
#pragma unroll
  for (int jj = 0; jj < 4; ++jj) {
    float4 lo = make_float4(accf[0 * 4 + jj], accf[1 * 4 + jj], accf[2 * 4 + jj], accf[3 * 4 + jj]);
    float4 hi = make_float4(accf[4 * 4 + jj], accf[5 * 4 + jj], accf[6 * 4 + jj], accf[7 * 4 + jj]);
    *(float4*)(simTn + (size_t)(jb + jj) * G0N + ib)     = lo;
    *(float4*)(simTn + (size_t)(jb + jj) * G0N + ib + 4) = hi;
  }
}

// ---------------- K2: top-8 per row (one wave / row), JAX tie-break ----------------
__global__ __launch_bounds__(256) void k_topk(const float* __restrict__ sim,
                                              const float* __restrict__ simT,
                                              int* __restrict__ i01,
                                              int* __restrict__ i10) {
  int wid  = (blockIdx.x * 256 + threadIdx.x) >> 6;  // 0..6399
  int lane = threadIdx.x & 63;
  int dir  = wid / (N_B * G0N);
  int r    = wid - dir * (N_B * G0N);
  const float* row = (dir ? simT : sim) + (size_t)r * G0N;
  int* out = (dir ? i10 : i01) + r * TK;

  float v[25];
#pragma unroll
  for (int tt = 0; tt < 25; ++tt) v[tt] = row[lane + 64 * tt];

#pragma unroll 1
  for (int k = 0; k < TK; ++k) {
    float best = -3.4e38f; int bidx = 0x7fffffff;
#pragma unroll
    for (int tt = 0; tt < 25; ++tt) {
      if (v[tt] > best) { best = v[tt]; bidx = lane + 64 * tt; }
    }
#pragma unroll
    for (int off = 1; off < 64; off <<= 1) {
      float ov = __shfl_xor(best, off);
      int   oi = __shfl_xor(bidx, off);
      if (ov > best || (ov == best && oi < bidx)) { best = ov; bidx = oi; }
    }
    if (lane == 0) out[k] = bidx;
#pragma unroll
    for (int tt = 0; tt < 25; ++tt)
      if (lane + 64 * tt == bidx) v[tt] = -3.4e38f;
  }
}

// ---------------- K3: pre-softmax heatmaps, v4: LDS-x + hoisted att loads ----------------
// v1 (36.5KB LDS): 86us, Occ 18%. v2 (per-lane stream): 115us, 8x line-reqs. REVERTED.
// v3 (coalesced, 36 VGPR): 86us, Occ 65%, VALU 10% -- latency-bound: compiler
//     serialized ~8 load->waitcnt->fma round-trips/thread (no VGPRs to hoist).
// v4: x (4KB) staged to LDS (kills 128/160 VMEM instrs per block); all 8 att
//     float4s hoisted to registers up-front (8 wave-instrs x 8 lines in flight,
//     ONE vmcnt drain). VGPR 36 -> ~60 deliberately: registers buy MLP.
// Math order identical to v3 -> bitwise-same output.
__global__ __launch_bounds__(256) void k_heat(const float* __restrict__ x0,
                                              const float* __restrict__ a01,
                                              float* __restrict__ h01p,
                                              const float* __restrict__ x1,
                                              const float* __restrict__ a10,
                                              float* __restrict__ h10p) {
  int bid = blockIdx.x;   // 0..6399
  const float* x   = x0;
  const float* att = a01;
  float*      hpre = h01p;
  int ng = bid;
  if (bid >= N_B * G0N) { x = x1; att = a10; hpre = h10p; ng = bid - N_B * G0N; }
  const int t = threadIdx.x;

  __shared__ float xs[4 * C_DIM];   // 4KB
  __shared__ float dots[4][33];     // [q][k4], padded
  *(float4*)&xs[t * 4] = *(const float4*)(x + (size_t)ng * 4 * C_DIM + t * 4);

  const int row = t >> 3;   // att row k4: 0..31
  const int sub = t & 7;    // c-chunk: 0..7
  const float* ar = att + ((size_t)ng * 32 + row) * C_DIM + sub * 4;
  // hoist all 8 att float4s: independent loads, deep vmcnt pipeline
  float4 av[8];
#pragma unroll
  for (int it = 0; it < 8; ++it) av[it] = *(const float4*)(ar + it * 32);

  __syncthreads();

  float a0 = 0.f, a1 = 0.f, a2 = 0.f, a3 = 0.f;
#pragma unroll
  for (int it = 0; it < 8; ++it) {
    const int xo = sub * 4 + it * 32;
    float4 xv0 = *(const float4*)&xs[0 * C_DIM + xo];
    float4 xv1 = *(const float4*)&xs[1 * C_DIM + xo];
    float4 xv2 = *(const float4*)&xs[2 * C_DIM + xo];
    float4 xv3 = *(const float4*)&xs[3 * C_DIM + xo];
    a0 += av[it].x * xv0.x + av[it].y * xv0.y + av[it].z * xv0.z + av[it].w * xv0.w;
    a1 += av[it].x * xv1.x + av[it].y * xv1.y + av[it].z * xv1.z + av[it].w * xv1.w;
    a2 += av[it].x * xv2.x + av[it].y * xv2.y + av[it].z * xv2.z + av[it].w * xv2.w;
    a3 += av[it].x * xv3.x + av[it].y * xv3.y + av[it].z * xv3.z + av[it].w * xv3.w;
  }
  // reduce the 8 c-chunks (lanes row*8+sub, sub=0..7): xor 1,2,4
#pragma unroll
  for (int off = 1; off < 8; off <<= 1) {
    a0 += __shfl_xor(a0, off);
    a1 += __shfl_xor(a1, off);
    a2 += __shfl_xor(a2, off);
    a3 += __shfl_xor(a3, off);
  }
  if (sub == 0) {
    dots[0][row] = a0;
    dots[1][row] = a1;
    dots[2][row] = a2;
    dots[3][row] = a3;
  }
  __syncthreads();
  if (t < 128) {
    int q = t >> 5, k4 = t & 31;
    float l = (dots[q][k4] * (1.0f / 256.0f)) / 0.1f;  // /C then /TEMP, reference order
    float m = l;
#pragma unroll
    for (int off = 1; off < 32; off <<= 1) m = fmaxf(m, __shfl_xor(m, off));
    float e = expf(l - m);
    float s = e;
#pragma unroll
    for (int off = 1; off < 32; off <<= 1) s += __shfl_xor(s, off);
    hpre[(size_t)ng * 128 + q * 32 + k4] = e / s;
  }
}

// ---------------- K4: fused mutual-mask + argmax (merged 01|10 halves) ----------------
// blocks [0,1600): h01 path (score/jbest); [1600,3200): h10 path (ibest).
__global__ __launch_bounds__(256) void k_fuse(const float* __restrict__ h01p,
                                              const float* __restrict__ h10p,
                                              const int* __restrict__ i01,
                                              const int* __restrict__ i10,
                                              float* __restrict__ h01_out,
                                              float* __restrict__ h10_out,
                                              float* __restrict__ score_ws,
                                              int* __restrict__ jbest_ws,
                                              float* __restrict__ jbest_out,
                                              int* __restrict__ ibest_ws) {
  if (blockIdx.x < 1600) {
    int idx = blockIdx.x * 8 + (threadIdx.x >> 5);  // (n,l0)
    int k4  = threadIdx.x & 31;
    int n = idx / L0N, l0 = idx - n * L0N;
    int r0 = l0 / W_F, c0 = l0 - r0 * W_F;
    int g0 = (r0 >> 1) * GW + (c0 >> 1);
    int q0 = ((r0 & 1) << 1) | (c0 & 1);
    int k = k4 >> 2, g = k4 & 3;
    int jc = i01[(n * G0N + g0) * TK + k];
    // mutual check: exists k' with i10[n][jc][k'] == g0; q1(j)=g
    const int* row10 = i10 + (n * G0N + jc) * TK;
    int kf = -1;
#pragma unroll
    for (int kp = 0; kp < 8; ++kp) if (row10[kp] == g0) kf = kp;
    float m = 0.f;
    if (kf >= 0) m = h10p[((n * G0N + jc) * 4 + g) * 32 + kf * 4 + q0];
    float h = h01p[((n * G0N + g0) * 4 + q0) * 32 + k4];
    float val = h * m;
    h01_out[(size_t)idx * 32 + k4] = val;

    float best = val; int bi = k4;  // first-argmax: min index on ties
#pragma unroll
    for (int off = 1; off < 32; off <<= 1) {
      float ov = __shfl_xor(best, off);
      int   oi = __shfl_xor(bi, off);
      if (ov > best || (ov == best && oi < bi)) { best = ov; bi = oi; }
    }
    if (k4 == 0) {
      score_ws[idx] = best;
      int kB = bi >> 2, gB = bi & 3;
      int jcB = i01[(n * G0N + g0) * TK + kB];
      int jrow = jcB / GW;
      int jb = ((jrow * 2 + (gB >> 1)) * W_F) + (jcB - jrow * GW) * 2 + (gB & 1);
      if (r0 < 2 || r0 >= W_F - 2 || c0 < 2 || c0 >= W_F - 2) jb = 0;  // border on position
      jbest_ws[idx]  = jb;
      jbest_out[idx] = (float)jb;
    }
  } else {
    int idx = (blockIdx.x - 1600) * 8 + (threadIdx.x >> 5);  // (n,l1)
    int k4  = threadIdx.x & 31;
    int n = idx / L0N, l1 = idx - n * L0N;
    int r1 = l1 / W_F, c1 = l1 - r1 * W_F;
    int g1 = (r1 >> 1) * GW + (c1 >> 1);
    int q1 = ((r1 & 1) << 1) | (c1 & 1);
    int k = k4 >> 2, g = k4 & 3;
    int ic = i10[(n * G0N + g1) * TK + k];
    const int* row01 = i01 + (n * G0N + ic) * TK;
    int kf = -1;
#pragma unroll
    for (int kp = 0; kp < 8; ++kp) if (row01[kp] == g1) kf = kp;
    float m = 0.f;
    if (kf >= 0) m = h01p[((n * G0N + ic) * 4 + g) * 32 + kf * 4 + q1];
    float h = h10p[((n * G0N + g1) * 4 + q1) * 32 + k4];
    float val = h * m;
    h10_out[((size_t)n * 32 + k4) * L0N + l1] = val;

    float best = val; int bi = k4;
#pragma unroll
    for (int off = 1; off < 32; off <<= 1) {
      float ov = __shfl_xor(best, off);
      int   oi = __shfl_xor(bi, off);
      if (ov > best || (ov == best && oi < bi)) { best = ov; bi = oi; }
    }
    if (k4 == 0) {
      int kB = bi >> 2, gB = bi & 3;
      int icB = i10[(n * G0N + g1) * TK + kB];
      int irow = icB / GW;
      int ib = ((irow * 2 + (gB >> 1)) * W_F) + (icB - irow * GW) * 2 + (gB & 1);
      if (r1 < 2 || r1 >= W_F - 2 || c1 < 2 || c1 >= W_F - 2) ib = 0;
      ibest_ws[idx] = ib;
    }
  }
}

// ---------------- K5: bi-projection mask + masked scores ----------------
__global__ __launch_bounds__(256) void k_final(const float* __restrict__ score_ws,
                                               const int* __restrict__ jbest_ws,
                                               const int* __restrict__ ibest_ws,
                                               float* __restrict__ scores_out,
                                               float* __restrict__ mask_out) {
  int idx = blockIdx.x * 256 + threadIdx.x;
  if (idx >= N_B * L0N) return;
  int n = idx / L0N, l0 = idx - n * L0N;
  int jb = jbest_ws[idx];
  float sc = score_ws[idx];
  int biproj = ibest_ws[n * L0N + jb];
  bool mk = (biproj == l0) && (l0 != 0) && (sc > 0.2f);
  scores_out[idx] = mk ? sc : 0.f;
  mask_out[idx]   = mk ? 1.f : 0.f;
}

// ---------------- K6: unpatchify via 32x32 LDS transpose tiles ----------------
// merged: blockIdx.z in [0,16) -> (x0 -> out0); [16,32) -> (x1 -> out1)
__global__ __launch_bounds__(256) void k_unpatch(const float* __restrict__ x0,
                                                 float* __restrict__ out0,
                                                 const float* __restrict__ x1,
                                                 float* __restrict__ out1) {
  __shared__ float tile[32][33];
  int z = blockIdx.z;
  const float* x = (z < 16) ? x0 : x1;
  float* out     = (z < 16) ? out0 : out1;
  int zz  = z & 15;
  int cc0 = blockIdx.x * 32;
  int r   = blockIdx.y;
  int n   = zz >> 3;
  int c0  = (zz & 7) * 32;
  int t = threadIdx.x;
  int sr = r & 1, ghr = r >> 1;
  int pos = t >> 5, cl = t & 31;
#pragma unroll
  for (int it = 0; it < 4; ++it) {
    int p = pos + it * 8;
    int cc = cc0 + p;
    if (cc < W_F) {
      int gg = ghr * GW + (cc >> 1);
      int qq = (sr << 1) | (cc & 1);
      tile[p][cl] = x[(((size_t)n * G0N + gg) * 4 + qq) * C_DIM + c0 + cl];
    }
  }
  __syncthreads();
  int co = t >> 5, p2 = t & 31;
#pragma unroll
  for (int it = 0; it < 4; ++it) {
    int c = c0 + co + it * 8;
    int cc = cc0 + p2;
    if (cc < W_F)
      out[(((size_t)n * C_DIM + c) * W_F + r) * W_F + cc] = tile[p2][co + it * 8];
  }
}

extern "C" void kernel_launch(void* const* d_in, const int* in_sizes, int n_in,
                              void* d_out, int out_size, void* d_ws, size_t ws_size,
                              hipStream_t stream) {
  const float* x0  = (const float*)d_in[0];
  const float* x1  = (const float*)d_in[1];
  const float* a01 = (const float*)d_in[2];
  const float* a10 = (const float*)d_in[3];
  const float* p0  = (const float*)d_in[4];
  const float* p1  = (const float*)d_in[5];
  float* out = (float*)d_out;

  float* ws       = (float*)d_ws;
  float* sim      = ws;                      // 2*1600*1600
  float* simT     = ws + 5120000;            // 2*1600*1600
  int*   i01      = (int*)(ws + 10240000);   // 2*1600*8
  int*   i10      = (int*)(ws + 10265600);
  float* h01p     = ws + 10291200;           // 2*1600*4*32
  float* h10p     = ws + 10700800;
  float* score_ws = ws + 11110400;           // 2*6400
  int*   jbest_ws = (int*)(ws + 11123200);
  int*   ibest_ws = (int*)(ws + 11136000);   // end: 11,148,800 floats (~44.6MB)

  float* o_h01   = out;
  float* o_h10   = out + 409600;
  float* o_score = out + 819200;
  float* o_jbest = out + 832000;
  float* o_mask  = out + 844800;
  float* o_x08   = out + 857600;
  float* o_x18   = out + 4134400;

  k_sim<<<dim3(25, 25, 2), 128, 0, stream>>>(p0, p1, sim, simT);
  k_topk<<<1600, 256, 0, stream>>>(sim, simT, i01, i10);
  k_heat<<<6400, 256, 0, stream>>>(x0, a01, h01p, x1, a10, h10p);
  k_fuse<<<3200, 256, 0, stream>>>(h01p, h10p, i01, i10, o_h01, o_h10,
                                   score_ws, jbest_ws, o_jbest, ibest_ws);
  k_final<<<50, 256, 0, stream>>>(score_ws, jbest_ws, ibest_ws, o_score, o_mask);
  k_unpatch<<<dim3(3, 80, 32), 256, 0, stream>>>(x0, o_x08, x1, o_x18);
}

// Round 5
// 324.227 us; speedup vs baseline: 1.0447x; 1.0447x over previous
//
#include <hip/hip_runtime.h>

// CoarseMatching on MI355X.
// Sizes: N=2, C=256, G0=G1=1600 (40x40), L0=L1=6400 (80x80), TOPK=8, K4=32.
// Outputs (flat f32, concat): h01 (2,6400,32) | h10 (2,32,6400) | scores (2,6400)
//   | j_best (2,6400, int-as-float) | mask (2,6400, 0/1) | x0_8x (2,256,80,80) | x1_8x.
// Workspace: sim + simT (40.96MB) + topk idx + h01p/h10p + score/jbest/ibest ~= 44.6MB.
//
// R4 restructure: k_heat(86us, HBM-heavy, VALU 10%) + k_sim(~30us, VALU-heavy,
// HBM 13%) + k_unpatch(~10us, copy) are mutually independent and pipe-complementary
// -> ONE mega-dispatch partitioned by blockIdx (heat first, sim fills its memory-wait
// bubbles, unpatch drains). 7 launches -> 4. sim retiled to 256thr/4x4, same
// ascending-k accumulation order -> bitwise-identical results everywhere.

#define N_B   2
#define C_DIM 256
#define G0N   1600
#define GW    40
#define L0N   6400
#define W_F   80
#define TK    8

#define KC 32
// mega-grid layout
#define HEAT_N   6400
#define SIM_BASE 6400
#define SIM_N    1250
#define UNP_BASE 7650
#define UNP_N    7680
#define MEGA_N   15330

__global__ __launch_bounds__(256) void k_mega(
    const float* __restrict__ x0,  const float* __restrict__ a01, float* __restrict__ h01p,
    const float* __restrict__ x1,  const float* __restrict__ a10, float* __restrict__ h10p,
    const float* __restrict__ p0,  const float* __restrict__ p1,
    float* __restrict__ sim, float* __restrict__ simT,
    float* __restrict__ out0, float* __restrict__ out1) {
  __shared__ __align__(16) float lds[4096];   // 16KB union: sim As|Bs / heat xs|dots / unpatch tile
  const int bid = blockIdx.x;
  const int t   = threadIdx.x;

  if (bid < HEAT_N) {
    // ---------------- heat: pre-softmax heatmaps (v4 body, bitwise-same) ----------------
    const float* x   = x0;
    const float* att = a01;
    float*      hpre = h01p;
    int ng = bid;
    if (bid >= N_B * G0N) { x = x1; att = a10; hpre = h10p; ng = bid - N_B * G0N; }
    float* xs = lds;                                   // 1024 floats
    float (*dots)[33] = (float(*)[33])(lds + 1024);    // 4x33

    *(float4*)&xs[t * 4] = *(const float4*)(x + (size_t)ng * 4 * C_DIM + t * 4);

    const int row = t >> 3;   // att row k4: 0..31
    const int sub = t & 7;    // c-chunk: 0..7
    const float* ar = att + ((size_t)ng * 32 + row) * C_DIM + sub * 4;
    float4 av[8];
#pragma unroll
    for (int it = 0; it < 8; ++it) av[it] = *(const float4*)(ar + it * 32);

    __syncthreads();

    float a0 = 0.f, a1 = 0.f, a2 = 0.f, a3 = 0.f;
#pragma unroll
    for (int it = 0; it < 8; ++it) {
      const int xo = sub * 4 + it * 32;
      float4 xv0 = *(const float4*)&xs[0 * C_DIM + xo];
      float4 xv1 = *(const float4*)&xs[1 * C_DIM + xo];
      float4 xv2 = *(const float4*)&xs[2 * C_DIM + xo];
      float4 xv3 = *(const float4*)&xs[3 * C_DIM + xo];
      a0 += av[it].x * xv0.x + av[it].y * xv0.y + av[it].z * xv0.z + av[it].w * xv0.w;
      a1 += av[it].x * xv1.x + av[it].y * xv1.y + av[it].z * xv1.z + av[it].w * xv1.w;
      a2 += av[it].x * xv2.x + av[it].y * xv2.y + av[it].z * xv2.z + av[it].w * xv2.w;
      a3 += av[it].x * xv3.x + av[it].y * xv3.y + av[it].z * xv3.z + av[it].w * xv3.w;
    }
#pragma unroll
    for (int off = 1; off < 8; off <<= 1) {
      a0 += __shfl_xor(a0, off);
      a1 += __shfl_xor(a1, off);
      a2 += __shfl_xor(a2, off);
      a3 += __shfl_xor(a3, off);
    }
    if (sub == 0) {
      dots[0][row] = a0;
      dots[1][row] = a1;
      dots[2][row] = a2;
      dots[3][row] = a3;
    }
    __syncthreads();
    if (t < 128) {
      int q = t >> 5, k4 = t & 31;
      float l = (dots[q][k4] * (1.0f / 256.0f)) / 0.1f;  // /C then /TEMP, reference order
      float m = l;
#pragma unroll
      for (int off = 1; off < 32; off <<= 1) m = fmaxf(m, __shfl_xor(m, off));
      float e = expf(l - m);
      float s = e;
#pragma unroll
      for (int off = 1; off < 32; off <<= 1) s += __shfl_xor(s, off);
      hpre[(size_t)ng * 128 + q * 32 + k4] = e / s;
    }
  } else if (bid < UNP_BASE) {
    // ---------------- sim: A^T B GEMM + transpose (256thr, 4x4 micro-tile) ----------------
    // Same 64x64 tile, same KC=32, same ascending-k per-element accumulation order
    // as the R1 128-thread version -> bitwise-identical sim/simT.
    int s = bid - SIM_BASE;              // 0..1249
    const int n  = s / 625; s -= n * 625;
    const int i0 = (s / 25) * 64;
    const int j0 = (s % 25) * 64;
    const float* A = p0 + (size_t)n * C_DIM * G0N;  // [c][i]
    const float* B = p1 + (size_t)n * C_DIM * G0N;  // [c][j]
    float* As = lds;          // KC x 64
    float* Bs = lds + 2048;   // KC x 64
    const int tx = t & 15;    // 16 cols of 4 -> 64
    const int ty = t >> 4;    // 16 rows of 4 -> 64

    float4 acc[4];
#pragma unroll
    for (int ii = 0; ii < 4; ++ii) acc[ii] = make_float4(0.f, 0.f, 0.f, 0.f);

    for (int kc = 0; kc < C_DIM; kc += KC) {
#pragma unroll
      for (int u = 0; u < 2; ++u) {
        int f   = t + u * 256;        // 0..511
        int row = f >> 4;             // 16 float4 per row
        int c4  = (f & 15) * 4;
        *(float4*)&As[row * 64 + c4] = *(const float4*)(A + (size_t)(kc + row) * G0N + i0 + c4);
        *(float4*)&Bs[row * 64 + c4] = *(const float4*)(B + (size_t)(kc + row) * G0N + j0 + c4);
      }
      __syncthreads();
#pragma unroll
      for (int k = 0; k < KC; ++k) {
        __attribute__((aligned(16))) float a[4];
        *(float4*)&a[0] = *(const float4*)&As[k * 64 + ty * 4];
        float4 bv = *(const float4*)&Bs[k * 64 + tx * 4];
#pragma unroll
        for (int ii = 0; ii < 4; ++ii) {
          acc[ii].x += a[ii] * bv.x;
          acc[ii].y += a[ii] * bv.y;
          acc[ii].z += a[ii] * bv.z;
          acc[ii].w += a[ii] * bv.w;
        }
      }
      __syncthreads();
    }

    float* simn  = sim  + (size_t)n * G0N * G0N;
    float* simTn = simT + (size_t)n * G0N * G0N;
    const int ib = i0 + ty * 4;
    const int jb = j0 + tx * 4;
    const float* accf = (const float*)acc;  // [ii*4 + jj]
#pragma unroll
    for (int ii = 0; ii < 4; ++ii)
      *(float4*)(simn + (size_t)(ib + ii) * G0N + jb) = acc[ii];
#pragma unroll
    for (int jj = 0; jj < 4; ++jj) {
      float4 col = make_float4(accf[0 * 4 + jj], accf[1 * 4 + jj],
                               accf[2 * 4 + jj], accf[3 * 4 + jj]);
      *(float4*)(simTn + (size_t)(jb + jj) * G0N + ib) = col;
    }
  } else {
    // ---------------- unpatchify via 32x32 LDS transpose tiles ----------------
    int u = bid - UNP_BASE;               // 0..7679
    int ux = u % 3; u /= 3;
    int r  = u % 80; u /= 80;
    int z  = u;                            // 0..31
    const float* x = (z < 16) ? x0 : x1;
    float* out     = (z < 16) ? out0 : out1;
    int zz  = z & 15;
    int cc0 = ux * 32;
    int n   = zz >> 3;
    int c0  = (zz & 7) * 32;
    float (*tile)[33] = (float(*)[33])lds;
    int sr = r & 1, ghr = r >> 1;
    int pos = t >> 5, cl = t & 31;
#pragma unroll
    for (int it = 0; it < 4; ++it) {
      int p = pos + it * 8;
      int cc = cc0 + p;
      if (cc < W_F) {
        int gg = ghr * GW + (cc >> 1);
        int qq = (sr << 1) | (cc & 1);
        tile[p][cl] = x[(((size_t)n * G0N + gg) * 4 + qq) * C_DIM + c0 + cl];
      }
    }
    __syncthreads();
    int co = t >> 5, p2 = t & 31;
#pragma unroll
    for (int it = 0; it < 4; ++it) {
      int c = c0 + co + it * 8;
      int cc = cc0 + p2;
      if (cc < W_F)
        out[(((size_t)n * C_DIM + c) * W_F + r) * W_F + cc] = tile[p2][co + it * 8];
    }
  }
}

// ---------------- K2: top-8 per row (one wave / row), JAX tie-break ----------------
__global__ __launch_bounds__(256) void k_topk(const float* __restrict__ sim,
                                              const float* __restrict__ simT,
                                              int* __restrict__ i01,
                                              int* __restrict__ i10) {
  int wid  = (blockIdx.x * 256 + threadIdx.x) >> 6;  // 0..6399
  int lane = threadIdx.x & 63;
  int dir  = wid / (N_B * G0N);
  int r    = wid - dir * (N_B * G0N);
  const float* row = (dir ? simT : sim) + (size_t)r * G0N;
  int* out = (dir ? i10 : i01) + r * TK;

  float v[25];
#pragma unroll
  for (int tt = 0; tt < 25; ++tt) v[tt] = row[lane + 64 * tt];

#pragma unroll 1
  for (int k = 0; k < TK; ++k) {
    float best = -3.4e38f; int bidx = 0x7fffffff;
#pragma unroll
    for (int tt = 0; tt < 25; ++tt) {
      if (v[tt] > best) { best = v[tt]; bidx = lane + 64 * tt; }
    }
#pragma unroll
    for (int off = 1; off < 64; off <<= 1) {
      float ov = __shfl_xor(best, off);
      int   oi = __shfl_xor(bidx, off);
      if (ov > best || (ov == best && oi < bidx)) { best = ov; bidx = oi; }
    }
    if (lane == 0) out[k] = bidx;
#pragma unroll
    for (int tt = 0; tt < 25; ++tt)
      if (lane + 64 * tt == bidx) v[tt] = -3.4e38f;
  }
}

// ---------------- K4: fused mutual-mask + argmax (merged 01|10 halves) ----------------
// blocks [0,1600): h01 path (score/jbest); [1600,3200): h10 path (ibest).
__global__ __launch_bounds__(256) void k_fuse(const float* __restrict__ h01p,
                                              const float* __restrict__ h10p,
                                              const int* __restrict__ i01,
                                              const int* __restrict__ i10,
                                              float* __restrict__ h01_out,
                                              float* __restrict__ h10_out,
                                              float* __restrict__ score_ws,
                                              int* __restrict__ jbest_ws,
                                              float* __restrict__ jbest_out,
                                              int* __restrict__ ibest_ws) {
  if (blockIdx.x < 1600) {
    int idx = blockIdx.x * 8 + (threadIdx.x >> 5);  // (n,l0)
    int k4  = threadIdx.x & 31;
    int n = idx / L0N, l0 = idx - n * L0N;
    int r0 = l0 / W_F, c0 = l0 - r0 * W_F;
    int g0 = (r0 >> 1) * GW + (c0 >> 1);
    int q0 = ((r0 & 1) << 1) | (c0 & 1);
    int k = k4 >> 2, g = k4 & 3;
    int jc = i01[(n * G0N + g0) * TK + k];
    // mutual check: exists k' with i10[n][jc][k'] == g0; q1(j)=g
    const int* row10 = i10 + (n * G0N + jc) * TK;
    int kf = -1;
#pragma unroll
    for (int kp = 0; kp < 8; ++kp) if (row10[kp] == g0) kf = kp;
    float m = 0.f;
    if (kf >= 0) m = h10p[((n * G0N + jc) * 4 + g) * 32 + kf * 4 + q0];
    float h = h01p[((n * G0N + g0) * 4 + q0) * 32 + k4];
    float val = h * m;
    h01_out[(size_t)idx * 32 + k4] = val;

    float best = val; int bi = k4;  // first-argmax: min index on ties
#pragma unroll
    for (int off = 1; off < 32; off <<= 1) {
      float ov = __shfl_xor(best, off);
      int   oi = __shfl_xor(bi, off);
      if (ov > best || (ov == best && oi < bi)) { best = ov; bi = oi; }
    }
    if (k4 == 0) {
      score_ws[idx] = best;
      int kB = bi >> 2, gB = bi & 3;
      int jcB = i01[(n * G0N + g0) * TK + kB];
      int jrow = jcB / GW;
      int jb = ((jrow * 2 + (gB >> 1)) * W_F) + (jcB - jrow * GW) * 2 + (gB & 1);
      if (r0 < 2 || r0 >= W_F - 2 || c0 < 2 || c0 >= W_F - 2) jb = 0;  // border on position
      jbest_ws[idx]  = jb;
      jbest_out[idx] = (float)jb;
    }
  } else {
    int idx = (blockIdx.x - 1600) * 8 + (threadIdx.x >> 5);  // (n,l1)
    int k4  = threadIdx.x & 31;
    int n = idx / L0N, l1 = idx - n * L0N;
    int r1 = l1 / W_F, c1 = l1 - r1 * W_F;
    int g1 = (r1 >> 1) * GW + (c1 >> 1);
    int q1 = ((r1 & 1) << 1) | (c1 & 1);
    int k = k4 >> 2, g = k4 & 3;
    int ic = i10[(n * G0N + g1) * TK + k];
    const int* row01 = i01 + (n * G0N + ic) * TK;
    int kf = -1;
#pragma unroll
    for (int kp = 0; kp < 8; ++kp) if (row01[kp] == g1) kf = kp;
    float m = 0.f;
    if (kf >= 0) m = h01p[((n * G0N + ic) * 4 + g) * 32 + kf * 4 + q1];
    float h = h10p[((n * G0N + g1) * 4 + q1) * 32 + k4];
    float val = h * m;
    h10_out[((size_t)n * 32 + k4) * L0N + l1] = val;

    float best = val; int bi = k4;
#pragma unroll
    for (int off = 1; off < 32; off <<= 1) {
      float ov = __shfl_xor(best, off);
      int   oi = __shfl_xor(bi, off);
      if (ov > best || (ov == best && oi < bi)) { best = ov; bi = oi; }
    }
    if (k4 == 0) {
      int kB = bi >> 2, gB = bi & 3;
      int icB = i10[(n * G0N + g1) * TK + kB];
      int irow = icB / GW;
      int ib = ((irow * 2 + (gB >> 1)) * W_F) + (icB - irow * GW) * 2 + (gB & 1);
      if (r1 < 2 || r1 >= W_F - 2 || c1 < 2 || c1 >= W_F - 2) ib = 0;
      ibest_ws[idx] = ib;
    }
  }
}

// ---------------- K5: bi-projection mask + masked scores ----------------
__global__ __launch_bounds__(256) void k_final(const float* __restrict__ score_ws,
                                               const int* __restrict__ jbest_ws,
                                               const int* __restrict__ ibest_ws,
                                               float* __restrict__ scores_out,
                                               float* __restrict__ mask_out) {
  int idx = blockIdx.x * 256 + threadIdx.x;
  if (idx >= N_B * L0N) return;
  int n = idx / L0N, l0 = idx - n * L0N;
  int jb = jbest_ws[idx];
  float sc = score_ws[idx];
  int biproj = ibest_ws[n * L0N + jb];
  bool mk = (biproj == l0) && (l0 != 0) && (sc > 0.2f);
  scores_out[idx] = mk ? sc : 0.f;
  mask_out[idx]   = mk ? 1.f : 0.f;
}

extern "C" void kernel_launch(void* const* d_in, const int* in_sizes, int n_in,
                              void* d_out, int out_size, void* d_ws, size_t ws_size,
                              hipStream_t stream) {
  const float* x0  = (const float*)d_in[0];
  const float* x1  = (const float*)d_in[1];
  const float* a01 = (const float*)d_in[2];
  const float* a10 = (const float*)d_in[3];
  const float* p0  = (const float*)d_in[4];
  const float* p1  = (const float*)d_in[5];
  float* out = (float*)d_out;

  float* ws       = (float*)d_ws;
  float* sim      = ws;                      // 2*1600*1600
  float* simT     = ws + 5120000;            // 2*1600*1600
  int*   i01      = (int*)(ws + 10240000);   // 2*1600*8
  int*   i10      = (int*)(ws + 10265600);
  float* h01p     = ws + 10291200;           // 2*1600*4*32
  float* h10p     = ws + 10700800;
  float* score_ws = ws + 11110400;           // 2*6400
  int*   jbest_ws = (int*)(ws + 11123200);
  int*   ibest_ws = (int*)(ws + 11136000);   // end: 11,148,800 floats (~44.6MB)

  float* o_h01   = out;
  float* o_h10   = out + 409600;
  float* o_score = out + 819200;
  float* o_jbest = out + 832000;
  float* o_mask  = out + 844800;
  float* o_x08   = out + 857600;
  float* o_x18   = out + 4134400;

  k_mega<<<MEGA_N, 256, 0, stream>>>(x0, a01, h01p, x1, a10, h10p,
                                     p0, p1, sim, simT, o_x08, o_x18);
  k_topk<<<1600, 256, 0, stream>>>(sim, simT, i01, i10);
  k_fuse<<<3200, 256, 0, stream>>>(h01p, h10p, i01, i10, o_h01, o_h10,
                                   score_ws, jbest_ws, o_jbest, ibest_ws);
  k_final<<<50, 256, 0, stream>>>(score_ws, jbest_ws, ibest_ws, o_score, o_mask);
}

// Round 6
// 315.209 us; speedup vs baseline: 1.0746x; 1.0286x over previous
//
#include <hip/hip_runtime.h>

// CoarseMatching on MI355X.
// Sizes: N=2, C=256, G0=G1=1600 (40x40), L0=L1=6400 (80x80), TOPK=8, K4=32.
// Outputs (flat f32, concat): h01 (2,6400,32) | h10 (2,32,6400) | scores (2,6400)
//   | j_best (2,6400, int-as-float) | mask (2,6400, 0/1) | x0_8x (2,256,80,80) | x1_8x.
//
// R5: (a) Bresenham-interleave heat/sim/unpatch roles across the mega grid so all
// three pipe-profiles are co-resident the whole dispatch (R5 counters proved the
// contiguous layout gave ZERO overlap: 136us = 86+30+10+gaps).
// (b) heat v5: 1600 blocks x 4 units, att double-buffered in REGISTERS across units,
// next-unit loads pinned above current-unit FMAs with sched_barrier(0) (v4 showed
// VGPR=32: compiler sank the hoist; the fence forbids that). Math order unchanged
// -> bitwise-identical outputs.

#define N_B   2
#define C_DIM 256
#define G0N   1600
#define GW    40
#define L0N   6400
#define W_F   80
#define TK    8

#define KC 32
// mega-grid: 1600 heat + 1250 sim + 7680 unpatch = 10530, striped.
#define MEGA_N   10530

__global__ __launch_bounds__(256, 4) void k_mega(
    const float* __restrict__ x0,  const float* __restrict__ a01, float* __restrict__ h01p,
    const float* __restrict__ x1,  const float* __restrict__ a10, float* __restrict__ h10p,
    const float* __restrict__ p0,  const float* __restrict__ p1,
    float* __restrict__ sim, float* __restrict__ simT,
    float* __restrict__ out0, float* __restrict__ out1) {
  __shared__ __align__(16) float lds[4624];  // heat: xs 4096 + dots 528 | sim: 4096 | unp: 1056
  const int bid = blockIdx.x;
  const int t   = threadIdx.x;

  // ---- role striping: heat 160/1053, then sim 125/893 of the rest (exact) ----
  int hq = bid * 160;
  bool is_heat = (hq % 1053) < 160;
  int hid = hq / 1053;
  int r2 = bid - (hq + 1052) / 1053;       // rest index (non-heat)
  int sq = r2 * 125;
  bool is_sim = (sq % 893) < 125;
  int sid = sq / 893;
  int uid = r2 - (sq + 892) / 893;

  if (is_heat) {
    // ---------------- heat v5: 4 units, register-pipelined att ----------------
    const float* x   = x0;
    const float* att = a01;
    float*      hpre = h01p;
    int ng0 = hid * 4;
    if (ng0 >= N_B * G0N) { x = x1; att = a10; hpre = h10p; ng0 -= N_B * G0N; }

    const int row = t >> 3;   // att row k4: 0..31
    const int sub = t & 7;    // c-chunk: 0..7
    const float* arb = att + ((size_t)ng0 * 32 + row) * C_DIM + sub * 4;

    // prologue: issue unit0 att loads, then stage x for all 4 units (16KB, coalesced)
    float4 av[2][8];
#pragma unroll
    for (int it = 0; it < 8; ++it) av[0][it] = *(const float4*)(arb + it * 32);
    const float* xb = x + (size_t)ng0 * 4 * C_DIM;   // 4 units contiguous: 4096 floats
#pragma unroll
    for (int j = 0; j < 4; ++j) {
      int f = t + j * 256;
      *(float4*)&lds[f * 4] = *(const float4*)(xb + (size_t)f * 4);
    }
    float* dots = lds + 4096;  // [u*4+q][33]
    __syncthreads();

#pragma unroll
    for (int u = 0; u < 4; ++u) {
      if (u < 3) {
        const float* arn = arb + (size_t)(u + 1) * (32 * C_DIM);
#pragma unroll
        for (int it = 0; it < 8; ++it) av[(u + 1) & 1][it] = *(const float4*)(arn + it * 32);
      }
      __builtin_amdgcn_sched_barrier(0);   // pin prefetch above this unit's FMAs
      float a0 = 0.f, a1 = 0.f, a2 = 0.f, a3 = 0.f;
#pragma unroll
      for (int it = 0; it < 8; ++it) {
        const float4 avv = av[u & 1][it];
        const int xo = u * 1024 + sub * 4 + it * 32;
        float4 xv0 = *(const float4*)&lds[xo + 0 * C_DIM];
        float4 xv1 = *(const float4*)&lds[xo + 1 * C_DIM];
        float4 xv2 = *(const float4*)&lds[xo + 2 * C_DIM];
        float4 xv3 = *(const float4*)&lds[xo + 3 * C_DIM];
        a0 += avv.x * xv0.x + avv.y * xv0.y + avv.z * xv0.z + avv.w * xv0.w;
        a1 += avv.x * xv1.x + avv.y * xv1.y + avv.z * xv1.z + avv.w * xv1.w;
        a2 += avv.x * xv2.x + avv.y * xv2.y + avv.z * xv2.z + avv.w * xv2.w;
        a3 += avv.x * xv3.x + avv.y * xv3.y + avv.z * xv3.z + avv.w * xv3.w;
      }
#pragma unroll
      for (int off = 1; off < 8; off <<= 1) {
        a0 += __shfl_xor(a0, off);
        a1 += __shfl_xor(a1, off);
        a2 += __shfl_xor(a2, off);
        a3 += __shfl_xor(a3, off);
      }
      if (sub == 0) {
        dots[(u * 4 + 0) * 33 + row] = a0;
        dots[(u * 4 + 1) * 33 + row] = a1;
        dots[(u * 4 + 2) * 33 + row] = a2;
        dots[(u * 4 + 3) * 33 + row] = a3;
      }
    }
    __syncthreads();
    // softmax: 16 (u,q) groups x 32 lanes; 256 threads -> 2 groups each
    const int lane32 = t & 31;
    const int g0 = t >> 5;      // 0..7
#pragma unroll
    for (int p = 0; p < 2; ++p) {
      int grp = g0 + p * 8;     // 0..15
      int u = grp >> 2, q = grp & 3;
      float l = (dots[grp * 33 + lane32] * (1.0f / 256.0f)) / 0.1f;  // /C then /TEMP
      float m = l;
#pragma unroll
      for (int off = 1; off < 32; off <<= 1) m = fmaxf(m, __shfl_xor(m, off));
      float e = expf(l - m);
      float s = e;
#pragma unroll
      for (int off = 1; off < 32; off <<= 1) s += __shfl_xor(s, off);
      hpre[(size_t)(ng0 + u) * 128 + q * 32 + lane32] = e / s;
    }
  } else if (is_sim) {
    // ---------------- sim: A^T B GEMM + transpose (256thr, 4x4 micro-tile) ----------------
    // byte-identical math to R5 (bitwise-same sim/simT)
    int s = sid;                         // 0..1249
    const int n  = s / 625; s -= n * 625;
    const int i0 = (s / 25) * 64;
    const int j0 = (s % 25) * 64;
    const float* A = p0 + (size_t)n * C_DIM * G0N;  // [c][i]
    const float* B = p1 + (size_t)n * C_DIM * G0N;  // [c][j]
    float* As = lds;          // KC x 64
    float* Bs = lds + 2048;   // KC x 64
    const int tx = t & 15;    // 16 cols of 4 -> 64
    const int ty = t >> 4;    // 16 rows of 4 -> 64

    float4 acc[4];
#pragma unroll
    for (int ii = 0; ii < 4; ++ii) acc[ii] = make_float4(0.f, 0.f, 0.f, 0.f);

    for (int kc = 0; kc < C_DIM; kc += KC) {
#pragma unroll
      for (int u = 0; u < 2; ++u) {
        int f   = t + u * 256;        // 0..511
        int rw  = f >> 4;             // 16 float4 per row
        int c4  = (f & 15) * 4;
        *(float4*)&As[rw * 64 + c4] = *(const float4*)(A + (size_t)(kc + rw) * G0N + i0 + c4);
        *(float4*)&Bs[rw * 64 + c4] = *(const float4*)(B + (size_t)(kc + rw) * G0N + j0 + c4);
      }
      __syncthreads();
#pragma unroll
      for (int k = 0; k < KC; ++k) {
        __attribute__((aligned(16))) float a[4];
        *(float4*)&a[0] = *(const float4*)&As[k * 64 + ty * 4];
        float4 bv = *(const float4*)&Bs[k * 64 + tx * 4];
#pragma unroll
        for (int ii = 0; ii < 4; ++ii) {
          acc[ii].x += a[ii] * bv.x;
          acc[ii].y += a[ii] * bv.y;
          acc[ii].z += a[ii] * bv.z;
          acc[ii].w += a[ii] * bv.w;
        }
      }
      __syncthreads();
    }

    float* simn  = sim  + (size_t)n * G0N * G0N;
    float* simTn = simT + (size_t)n * G0N * G0N;
    const int ib = i0 + ty * 4;
    const int jb = j0 + tx * 4;
    const float* accf = (const float*)acc;  // [ii*4 + jj]
#pragma unroll
    for (int ii = 0; ii < 4; ++ii)
      *(float4*)(simn + (size_t)(ib + ii) * G0N + jb) = acc[ii];
#pragma unroll
    for (int jj = 0; jj < 4; ++jj) {
      float4 col = make_float4(accf[0 * 4 + jj], accf[1 * 4 + jj],
                               accf[2 * 4 + jj], accf[3 * 4 + jj]);
      *(float4*)(simTn + (size_t)(jb + jj) * G0N + ib) = col;
    }
  } else {
    // ---------------- unpatchify via 32x32 LDS transpose tiles ----------------
    int u = uid;                          // 0..7679
    int ux = u % 3; u /= 3;
    int r  = u % 80; u /= 80;
    int z  = u;                           // 0..31
    const float* x = (z < 16) ? x0 : x1;
    float* out     = (z < 16) ? out0 : out1;
    int zz  = z & 15;
    int cc0 = ux * 32;
    int n   = zz >> 3;
    int c0  = (zz & 7) * 32;
    float (*tile)[33] = (float(*)[33])lds;
    int sr = r & 1, ghr = r >> 1;
    int pos = t >> 5, cl = t & 31;
#pragma unroll
    for (int it = 0; it < 4; ++it) {
      int p = pos + it * 8;
      int cc = cc0 + p;
      if (cc < W_F) {
        int gg = ghr * GW + (cc >> 1);
        int qq = (sr << 1) | (cc & 1);
        tile[p][cl] = x[(((size_t)n * G0N + gg) * 4 + qq) * C_DIM + c0 + cl];
      }
    }
    __syncthreads();
    int co = t >> 5, p2 = t & 31;
#pragma unroll
    for (int it = 0; it < 4; ++it) {
      int c = c0 + co + it * 8;
      int cc = cc0 + p2;
      if (cc < W_F)
        out[(((size_t)n * C_DIM + c) * W_F + r) * W_F + cc] = tile[p2][co + it * 8];
    }
  }
}

// ---------------- K2: top-8 per row (one wave / row), JAX tie-break ----------------
__global__ __launch_bounds__(256) void k_topk(const float* __restrict__ sim,
                                              const float* __restrict__ simT,
                                              int* __restrict__ i01,
                                              int* __restrict__ i10) {
  int wid  = (blockIdx.x * 256 + threadIdx.x) >> 6;  // 0..6399
  int lane = threadIdx.x & 63;
  int dir  = wid / (N_B * G0N);
  int r    = wid - dir * (N_B * G0N);
  const float* row = (dir ? simT : sim) + (size_t)r * G0N;
  int* out = (dir ? i10 : i01) + r * TK;

  float v[25];
#pragma unroll
  for (int tt = 0; tt < 25; ++tt) v[tt] = row[lane + 64 * tt];

#pragma unroll 1
  for (int k = 0; k < TK; ++k) {
    float best = -3.4e38f; int bidx = 0x7fffffff;
#pragma unroll
    for (int tt = 0; tt < 25; ++tt) {
      if (v[tt] > best) { best = v[tt]; bidx = lane + 64 * tt; }
    }
#pragma unroll
    for (int off = 1; off < 64; off <<= 1) {
      float ov = __shfl_xor(best, off);
      int   oi = __shfl_xor(bidx, off);
      if (ov > best || (ov == best && oi < bidx)) { best = ov; bidx = oi; }
    }
    if (lane == 0) out[k] = bidx;
#pragma unroll
    for (int tt = 0; tt < 25; ++tt)
      if (lane + 64 * tt == bidx) v[tt] = -3.4e38f;
  }
}

// ---------------- K4: fused mutual-mask + argmax (merged 01|10 halves) ----------------
__global__ __launch_bounds__(256) void k_fuse(const float* __restrict__ h01p,
                                              const float* __restrict__ h10p,
                                              const int* __restrict__ i01,
                                              const int* __restrict__ i10,
                                              float* __restrict__ h01_out,
                                              float* __restrict__ h10_out,
                                              float* __restrict__ score_ws,
                                              int* __restrict__ jbest_ws,
                                              float* __restrict__ jbest_out,
                                              int* __restrict__ ibest_ws) {
  if (blockIdx.x < 1600) {
    int idx = blockIdx.x * 8 + (threadIdx.x >> 5);  // (n,l0)
    int k4  = threadIdx.x & 31;
    int n = idx / L0N, l0 = idx - n * L0N;
    int r0 = l0 / W_F, c0 = l0 - r0 * W_F;
    int g0 = (r0 >> 1) * GW + (c0 >> 1);
    int q0 = ((r0 & 1) << 1) | (c0 & 1);
    int k = k4 >> 2, g = k4 & 3;
    int jc = i01[(n * G0N + g0) * TK + k];
    const int* row10 = i10 + (n * G0N + jc) * TK;
    int kf = -1;
#pragma unroll
    for (int kp = 0; kp < 8; ++kp) if (row10[kp] == g0) kf = kp;
    float m = 0.f;
    if (kf >= 0) m = h10p[((n * G0N + jc) * 4 + g) * 32 + kf * 4 + q0];
    float h = h01p[((n * G0N + g0) * 4 + q0) * 32 + k4];
    float val = h * m;
    h01_out[(size_t)idx * 32 + k4] = val;

    float best = val; int bi = k4;  // first-argmax: min index on ties
#pragma unroll
    for (int off = 1; off < 32; off <<= 1) {
      float ov = __shfl_xor(best, off);
      int   oi = __shfl_xor(bi, off);
      if (ov > best || (ov == best && oi < bi)) { best = ov; bi = oi; }
    }
    if (k4 == 0) {
      score_ws[idx] = best;
      int kB = bi >> 2, gB = bi & 3;
      int jcB = i01[(n * G0N + g0) * TK + kB];
      int jrow = jcB / GW;
      int jb = ((jrow * 2 + (gB >> 1)) * W_F) + (jcB - jrow * GW) * 2 + (gB & 1);
      if (r0 < 2 || r0 >= W_F - 2 || c0 < 2 || c0 >= W_F - 2) jb = 0;  // border on position
      jbest_ws[idx]  = jb;
      jbest_out[idx] = (float)jb;
    }
  } else {
    int idx = (blockIdx.x - 1600) * 8 + (threadIdx.x >> 5);  // (n,l1)
    int k4  = threadIdx.x & 31;
    int n = idx / L0N, l1 = idx - n * L0N;
    int r1 = l1 / W_F, c1 = l1 - r1 * W_F;
    int g1 = (r1 >> 1) * GW + (c1 >> 1);
    int q1 = ((r1 & 1) << 1) | (c1 & 1);
    int k = k4 >> 2, g = k4 & 3;
    int ic = i10[(n * G0N + g1) * TK + k];
    const int* row01 = i01 + (n * G0N + ic) * TK;
    int kf = -1;
#pragma unroll
    for (int kp = 0; kp < 8; ++kp) if (row01[kp] == g1) kf = kp;
    float m = 0.f;
    if (kf >= 0) m = h01p[((n * G0N + ic) * 4 + g) * 32 + kf * 4 + q1];
    float h = h10p[((n * G0N + g1) * 4 + q1) * 32 + k4];
    float val = h * m;
    h10_out[((size_t)n * 32 + k4) * L0N + l1] = val;

    float best = val; int bi = k4;
#pragma unroll
    for (int off = 1; off < 32; off <<= 1) {
      float ov = __shfl_xor(best, off);
      int   oi = __shfl_xor(bi, off);
      if (ov > best || (ov == best && oi < bi)) { best = ov; bi = oi; }
    }
    if (k4 == 0) {
      int kB = bi >> 2, gB = bi & 3;
      int icB = i10[(n * G0N + g1) * TK + kB];
      int irow = icB / GW;
      int ib = ((irow * 2 + (gB >> 1)) * W_F) + (icB - irow * GW) * 2 + (gB & 1);
      if (r1 < 2 || r1 >= W_F - 2 || c1 < 2 || c1 >= W_F - 2) ib = 0;
      ibest_ws[idx] = ib;
    }
  }
}

// ---------------- K5: bi-projection mask + masked scores ----------------
__global__ __launch_bounds__(256) void k_final(const float* __restrict__ score_ws,
                                               const int* __restrict__ jbest_ws,
                                               const int* __restrict__ ibest_ws,
                                               float* __restrict__ scores_out,
                                               float* __restrict__ mask_out) {
  int idx = blockIdx.x * 256 + threadIdx.x;
  if (idx >= N_B * L0N) return;
  int n = idx / L0N, l0 = idx - n * L0N;
  int jb = jbest_ws[idx];
  float sc = score_ws[idx];
  int biproj = ibest_ws[n * L0N + jb];
  bool mk = (biproj == l0) && (l0 != 0) && (sc > 0.2f);
  scores_out[idx] = mk ? sc : 0.f;
  mask_out[idx]   = mk ? 1.f : 0.f;
}

extern "C" void kernel_launch(void* const* d_in, const int* in_sizes, int n_in,
                              void* d_out, int out_size, void* d_ws, size_t ws_size,
                              hipStream_t stream) {
  const float* x0  = (const float*)d_in[0];
  const float* x1  = (const float*)d_in[1];
  const float* a01 = (const float*)d_in[2];
  const float* a10 = (const float*)d_in[3];
  const float* p0  = (const float*)d_in[4];
  const float* p1  = (const float*)d_in[5];
  float* out = (float*)d_out;

  float* ws       = (float*)d_ws;
  float* sim      = ws;                      // 2*1600*1600
  float* simT     = ws + 5120000;            // 2*1600*1600
  int*   i01      = (int*)(ws + 10240000);   // 2*1600*8
  int*   i10      = (int*)(ws + 10265600);
  float* h01p     = ws + 10291200;           // 2*1600*4*32
  float* h10p     = ws + 10700800;
  float* score_ws = ws + 11110400;           // 2*6400
  int*   jbest_ws = (int*)(ws + 11123200);
  int*   ibest_ws = (int*)(ws + 11136000);   // end: 11,148,800 floats (~44.6MB)

  float* o_h01   = out;
  float* o_h10   = out + 409600;
  float* o_score = out + 819200;
  float* o_jbest = out + 832000;
  float* o_mask  = out + 844800;
  float* o_x08   = out + 857600;
  float* o_x18   = out + 4134400;

  k_mega<<<MEGA_N, 256, 0, stream>>>(x0, a01, h01p, x1, a10, h10p,
                                     p0, p1, sim, simT, o_x08, o_x18);
  k_topk<<<1600, 256, 0, stream>>>(sim, simT, i01, i10);
  k_fuse<<<3200, 256, 0, stream>>>(h01p, h10p, i01, i10, o_h01, o_h10,
                                   score_ws, jbest_ws, o_jbest, ibest_ws);
  k_final<<<50, 256, 0, stream>>>(score_ws, jbest_ws, ibest_ws, o_score, o_mask);
}